// Round 5
// baseline (1959.553 us; speedup 1.0000x reference)
//
#include <hip/hip_runtime.h>

typedef _Float16 half8 __attribute__((ext_vector_type(8)));
typedef _Float16 half4v __attribute__((ext_vector_type(4)));
typedef float floatx16 __attribute__((ext_vector_type(16)));
typedef float float4v __attribute__((ext_vector_type(4)));

#define MTOT 131072   // B*T rows
#define DDIM 1024
#define TLEN 4096
#define BATCH 32
#define NMASK 2048

__device__ __forceinline__ void gll16(const _Float16* g, const _Float16* l) {
  __builtin_amdgcn_global_load_lds(
      (const __attribute__((address_space(1))) void*)g,
      (__attribute__((address_space(3))) void*)l, 16, 0, 0);
}

// --------- kernel 0: transpose + fp16-split W1 (scaled by 2^9, exact) ---------
__global__ void k_wsplit(const float* __restrict__ W1, _Float16* __restrict__ Wthi,
                         _Float16* __restrict__ Wtlo)
{
  int flat = blockIdx.x * 256 + threadIdx.x;   // = e*1024 + d  (coalesced writes)
  int e = flat >> 10, d = flat & 1023;
  float w = W1[(size_t)d * DDIM + e] * 512.0f;
  _Float16 h = (_Float16)w;
  Wthi[flat] = h;
  Wtlo[flat] = (_Float16)(w - (float)h);
}

// --------- kernel 0b: fp16-split x (row-major, unscaled) ----------------------
__global__ void k_xsplit(const float* __restrict__ x, _Float16* __restrict__ xhi,
                         _Float16* __restrict__ xlo)
{
  const size_t n4 = (size_t)MTOT * DDIM / 4;
  for (size_t f = (size_t)blockIdx.x * blockDim.x + threadIdx.x; f < n4;
       f += (size_t)gridDim.x * blockDim.x) {
    float4v v = ((const float4v*)x)[f];
    half4v h, l;
#pragma unroll
    for (int i = 0; i < 4; i++) {
      _Float16 hh = (_Float16)v[i];
      h[i] = hh; l[i] = (_Float16)(v[i] - (float)hh);
    }
    ((half4v*)xhi)[f] = h;
    ((half4v*)xlo)[f] = l;
  }
}

// --------- kernel 1: fused scores GEMM ----------------------------------------
// tile 128x256, 8 waves (2x4), wave 64x64 = 2x2 frags of mfma_f32_32x32x16_f16.
// Monotone vmcnt queue per t-body: [B(t+1)->regs][gll A(t+1)->LDS][MFMA on B(t),
// LDS(t)][barrier]. Every wait retires only loads >=1500cyc old; barrier drain
// free. B reg-double-buffered (needs 256-reg budget: launch_bounds(512,2),
// 1 block/CU, 2 waves/SIMD — m201 regime).
__global__ __launch_bounds__(512, 2) void k_score(
    const _Float16* __restrict__ xhi, const _Float16* __restrict__ xlo,
    const _Float16* __restrict__ Wthi, const _Float16* __restrict__ Wtlo,
    const float* __restrict__ b1, const float* __restrict__ w2,
    float* __restrict__ partials)
{
  __shared__ __align__(16) _Float16 Abuf[2][2][128 * 64];   // [buf][hi/lo] 16KB each
  __shared__ float part_lds[4][128];

  const int tid  = threadIdx.x;
  const int lane = tid & 63;
  const int wave = tid >> 6;
  const int wr = wave >> 2, wn = wave & 3;
  const int l31 = lane & 31, l5 = lane >> 5;

  // XCD-bijective decode (id%8 = XCD): all 4 col-tiles of a row-panel go to the
  // SAME XCD -> panel enters that L2 once, reused 4x. 32 blocks/XCD cover 8
  // panels at a time = 4MB = L2-sized working set.
  const int id  = blockIdx.x;
  const int xcd = id & 7, seq = id >> 3;
  const int px  = seq & 3;                 // col-block 0..3
  const int py  = (seq >> 2) * 8 + xcd;    // row-panel 0..1023
  const int n0 = px * 256;
  const int m0 = py * 128;

  // gll inst q of wave w writes 16B-units d = w*128 + q*64 + lane (linear dest).
  // Unit d holds tile element (row d>>3, chunk (d&7) ^ (row&7)) -> swizzle the SOURCE.
  const int dq0 = wave * 128 + lane, dq1 = dq0 + 64;
  const int r0 = dq0 >> 3, s0 = dq0 & 7;
  const int r1 = dq1 >> 3, s1 = dq1 & 7;
  const _Float16* gh0 = xhi + (size_t)(m0 + r0) * DDIM + ((s0 ^ (r0 & 7)) * 8);
  const _Float16* gh1 = xhi + (size_t)(m0 + r1) * DDIM + ((s1 ^ (r1 & 7)) * 8);
  const _Float16* gl0 = xlo + (size_t)(m0 + r0) * DDIM + ((s0 ^ (r0 & 7)) * 8);
  const _Float16* gl1 = xlo + (size_t)(m0 + r1) * DDIM + ((s1 ^ (r1 & 7)) * 8);

  const _Float16* bsrc_hi[2];
  const _Float16* bsrc_lo[2];
#pragma unroll
  for (int nf = 0; nf < 2; nf++) {
    int col = n0 + wn * 64 + nf * 32 + l31;
    bsrc_hi[nf] = Wthi + (size_t)col * DDIM + l5 * 8;
    bsrc_lo[nf] = Wtlo + (size_t)col * DDIM + l5 * 8;
  }

  floatx16 acc[2][2] = {};
  half8 bA[4][2][2], bB[4][2][2];          // [kc][nf][hi/lo], static-indexed only

  // ---- prologue: B(0) -> bA; gll A(0) -> buf0 ----
#pragma unroll
  for (int kc = 0; kc < 4; kc++)
#pragma unroll
    for (int nf = 0; nf < 2; nf++) {
      bA[kc][nf][0] = *(const half8*)(bsrc_hi[nf] + kc * 16);
      bA[kc][nf][1] = *(const half8*)(bsrc_lo[nf] + kc * 16);
    }
  gll16(gh0, &Abuf[0][0][(wave * 2 + 0) * 512]);
  gll16(gh1, &Abuf[0][0][(wave * 2 + 1) * 512]);
  gll16(gl0, &Abuf[0][1][(wave * 2 + 0) * 512]);
  gll16(gl1, &Abuf[0][1][(wave * 2 + 1) * 512]);
  __syncthreads();

#define BODY(BUFC, BC, BN, T)                                                   \
  {                                                                             \
    if ((T) < 15) {                                                             \
      _Pragma("unroll")                                                         \
      for (int kc = 0; kc < 4; kc++)                                            \
        _Pragma("unroll")                                                       \
        for (int nf = 0; nf < 2; nf++) {                                        \
          BN[kc][nf][0] = *(const half8*)(bsrc_hi[nf] + ((T) + 1) * 64 + kc * 16); \
          BN[kc][nf][1] = *(const half8*)(bsrc_lo[nf] + ((T) + 1) * 64 + kc * 16); \
        }                                                                       \
      gll16(gh0 + ((T) + 1) * 64, &Abuf[(BUFC) ^ 1][0][(wave * 2 + 0) * 512]);  \
      gll16(gh1 + ((T) + 1) * 64, &Abuf[(BUFC) ^ 1][0][(wave * 2 + 1) * 512]);  \
      gll16(gl0 + ((T) + 1) * 64, &Abuf[(BUFC) ^ 1][1][(wave * 2 + 0) * 512]);  \
      gll16(gl1 + ((T) + 1) * 64, &Abuf[(BUFC) ^ 1][1][(wave * 2 + 1) * 512]);  \
    }                                                                           \
    _Pragma("unroll")                                                           \
    for (int kc = 0; kc < 4; kc++) {                                            \
      half8 ah[2], al[2];                                                       \
      _Pragma("unroll")                                                         \
      for (int mf = 0; mf < 2; mf++) {                                          \
        int r = wr * 64 + mf * 32 + l31;                                        \
        int u = r * 8 + ((kc * 2 + l5) ^ (r & 7));                              \
        ah[mf] = *(const half8*)&Abuf[BUFC][0][u * 8];                          \
        al[mf] = *(const half8*)&Abuf[BUFC][1][u * 8];                          \
      }                                                                         \
      _Pragma("unroll")                                                         \
      for (int mf = 0; mf < 2; mf++)                                            \
        _Pragma("unroll")                                                       \
        for (int nf = 0; nf < 2; nf++) {                                        \
          acc[mf][nf] = __builtin_amdgcn_mfma_f32_32x32x16_f16(ah[mf], BC[kc][nf][0], acc[mf][nf], 0, 0, 0); \
          acc[mf][nf] = __builtin_amdgcn_mfma_f32_32x32x16_f16(ah[mf], BC[kc][nf][1], acc[mf][nf], 0, 0, 0); \
          acc[mf][nf] = __builtin_amdgcn_mfma_f32_32x32x16_f16(al[mf], BC[kc][nf][0], acc[mf][nf], 0, 0, 0); \
        }                                                                       \
    }                                                                           \
    __syncthreads();                                                            \
  }

#pragma unroll 1
  for (int tt = 0; tt < 16; tt += 2) {
    BODY(0, bA, bB, tt)
    BODY(1, bB, bA, tt + 1)
  }
#undef BODY

  // ---- epilogue: tanh + dot(w2) + row reduce ----
  float b1v[2], w2v[2];
#pragma unroll
  for (int nf = 0; nf < 2; nf++) {
    int col = n0 + wn * 64 + nf * 32 + l31;
    b1v[nf] = b1[col];
    w2v[nf] = w2[col];
  }
  const float inv512 = 1.0f / 512.0f;
#pragma unroll
  for (int mf = 0; mf < 2; mf++)
#pragma unroll
    for (int reg = 0; reg < 16; reg++) {
      float s = 0.0f;
#pragma unroll
      for (int nf = 0; nf < 2; nf++) {
        float pre = acc[mf][nf][reg] * inv512 + b1v[nf];
        float a = fabsf(pre);
        float e = __expf(-2.0f * a);
        float t = (1.0f - e) / (1.0f + e);            // tanh(|pre|)
        s += copysignf(t, pre) * w2v[nf];
      }
#pragma unroll
      for (int off = 1; off < 32; off <<= 1) s += __shfl_xor(s, off, 64);
      if (l31 == 0)
        part_lds[wn][wr * 64 + mf * 32 + (reg & 3) + 8 * (reg >> 2) + 4 * l5] = s;
    }
  __syncthreads();
  if (tid < 128) {
    float v = part_lds[0][tid] + part_lds[1][tid] + part_lds[2][tid] + part_lds[3][tid];
    partials[(size_t)px * MTOT + m0 + tid] = v;
  }
}

// --------- kernel 2: per-batch-row exact select (stable-argsort semantics) + softmax
__global__ void k_select(const float* __restrict__ partials, const float* __restrict__ b2,
                         float* __restrict__ weights)
{
  __shared__ float s_lds[TLEN];
  __shared__ unsigned long long keys[TLEN];
  __shared__ float red[20];
  const int b = blockIdx.x, tid = threadIdx.x;
  const float b2v = b2[0];

  for (int i = tid; i < TLEN; i += 1024) {
    size_t idx = (size_t)b * TLEN + i;
    float s = partials[idx] + partials[idx + (size_t)MTOT] +
              partials[idx + 2 * (size_t)MTOT] + partials[idx + 3 * (size_t)MTOT] + b2v;
    s_lds[i] = s;
    unsigned u = __float_as_uint(s);
    u = (u & 0x80000000u) ? ~u : (u | 0x80000000u);  // order-preserving float->uint
    keys[i] = ((unsigned long long)u << 32) | (unsigned)i;
  }
  __syncthreads();
  // bitonic sort ascending (key = (score, index) — matches stable argsort)
  for (int k = 2; k <= TLEN; k <<= 1)
    for (int j = k >> 1; j > 0; j >>= 1) {
      for (int i = tid; i < TLEN; i += 1024) {
        int p = i ^ j;
        if (p > i) {
          unsigned long long a = keys[i], c = keys[p];
          bool up = ((i & k) == 0);
          if ((a > c) == up) { keys[i] = c; keys[p] = a; }
        }
      }
      __syncthreads();
    }

  const unsigned long long thr = keys[NMASK];        // first KEPT pair
  unsigned um = (unsigned)(keys[TLEN - 1] >> 32);    // decode row max
  um = (um & 0x80000000u) ? (um ^ 0x80000000u) : ~um;
  const float m = __uint_as_float(um);

  float ev[4]; bool kp[4]; float zp = 0.0f;
#pragma unroll
  for (int q = 0; q < 4; q++) {
    int i = tid + q * 1024;
    float s = s_lds[i];
    unsigned u = __float_as_uint(s);
    u = (u & 0x80000000u) ? ~u : (u | 0x80000000u);
    unsigned long long key = ((unsigned long long)u << 32) | (unsigned)i;
    kp[q] = (key >= thr);
    ev[q] = __expf(s - m);
    if (kp[q]) zp += ev[q];
  }
#pragma unroll
  for (int off = 1; off < 64; off <<= 1) zp += __shfl_xor(zp, off, 64);
  if ((tid & 63) == 0) red[tid >> 6] = zp;
  __syncthreads();
  if (tid == 0) { float z = 0.0f; for (int i = 0; i < 16; i++) z += red[i]; red[16] = z; }
  __syncthreads();
  const float invZ = 1.0f / red[16];
#pragma unroll
  for (int q = 0; q < 4; q++) {
    int i = tid + q * 1024;
    weights[(size_t)b * TLEN + i] = kp[q] ? ev[q] * invZ : 0.0f;
  }
}

// --------- kernel 3: masked_output = x * weights[row] ---------
__global__ void k_scale(const float* __restrict__ x, const float* __restrict__ weights,
                        float* __restrict__ out)
{
  const size_t n4 = (size_t)MTOT * DDIM / 4;
  for (size_t f = (size_t)blockIdx.x * blockDim.x + threadIdx.x; f < n4;
       f += (size_t)gridDim.x * blockDim.x) {
    float w = weights[f >> 8];                       // 256 float4 per row
    float4v v = ((const float4v*)x)[f];
    ((float4v*)out)[f] = v * w;
  }
}

extern "C" void kernel_launch(void* const* d_in, const int* in_sizes, int n_in,
                              void* d_out, int out_size, void* d_ws, size_t ws_size,
                              hipStream_t stream)
{
  const float* x  = (const float*)d_in[0];
  const float* W1 = (const float*)d_in[1];
  const float* b1 = (const float*)d_in[2];
  const float* w2 = (const float*)d_in[3];
  const float* b2 = (const float*)d_in[4];
  float* out = (float*)d_out;
  float* weights = out + (size_t)MTOT * DDIM;        // output 1 region

  // xhi/xlo scratch lives in d_out's masked_output region (512 MB, dead until
  // k_scale overwrites it at the end — sequential stream, deterministic).
  _Float16* xhi = (_Float16*)d_out;                  // 256 MiB
  _Float16* xlo = xhi + (size_t)MTOT * DDIM;         // 256 MiB

  char* ws = (char*)d_ws;
  _Float16* Wthi  = (_Float16*)ws;                   // 2 MiB
  _Float16* Wtlo  = (_Float16*)(ws + (2u << 20));    // 2 MiB
  float*    parts = (float*)(ws + (4u << 20));       // 4*131072*4 = 2 MiB

  k_wsplit<<<4096, 256, 0, stream>>>(W1, Wthi, Wtlo);
  k_xsplit<<<2048, 256, 0, stream>>>(x, xhi, xlo);
  k_score<<<4096, 512, 0, stream>>>(xhi, xlo, Wthi, Wtlo, b1, w2, parts);
  k_select<<<BATCH, 1024, 0, stream>>>(parts, b2, weights);
  k_scale<<<2048, 256, 0, stream>>>(x, weights, out);
}

// Round 7
// 1246.287 us; speedup vs baseline: 1.5723x; 1.5723x over previous
//
#include <hip/hip_runtime.h>

typedef _Float16 half8 __attribute__((ext_vector_type(8)));
typedef _Float16 half4v __attribute__((ext_vector_type(4)));
typedef float floatx16 __attribute__((ext_vector_type(16)));
typedef float float4v __attribute__((ext_vector_type(4)));

#define MTOT 131072   // B*T rows
#define DDIM 1024
#define TLEN 4096
#define BATCH 32
#define NMASK 2048

// --------- kernel 0: pack W1 into MFMA B-fragment order, fp16-split (x512) ----
// 2048 fragments: f = cb*64 + kb, cb in [0,32) covers cols cb*32..+31, kb in
// [0,64) covers k kb*16..+15. Wp[f][hl][lane][8]: lane l -> col cb*32+(l&31),
// k kb*16+(l>>5)*8+j. B-frag load in k_score = ONE coalesced 1KB wave-load.
__global__ void k_wpack(const float* __restrict__ W1, _Float16* __restrict__ Wp)
{
  const int f = blockIdx.x * 4 + (threadIdx.x >> 6);  // 0..2047
  const int l = threadIdx.x & 63;
  const int cb = f >> 6, kb = f & 63;
  const int col = cb * 32 + (l & 31);
  const int k0 = kb * 16 + (l >> 5) * 8;
  half8 hv, lv;
#pragma unroll
  for (int j = 0; j < 8; j++) {
    float w = W1[(size_t)(k0 + j) * DDIM + col] * 512.0f;
    _Float16 h = (_Float16)w;
    hv[j] = h; lv[j] = (_Float16)(w - (float)h);
  }
  *(half8*)(Wp + ((size_t)(f * 2 + 0) * 64 + l) * 8) = hv;
  *(half8*)(Wp + ((size_t)(f * 2 + 1) * 64 + l) * 8) = lv;
}

// --------- kernel 1: fused scores GEMM ----------------------------------------
// tile 128x256, 8 waves (2x4), wave 64x64 = 2x2 frags of mfma_f32_32x32x16_f16.
// B: coalesced fragment loads from Wp (L2-resident, reg-pipelined over kc).
// A: x fp32 loaded direct (T14: issue at top of step t for t+1), split to hi/lo
// f16 in regs, stride-136 LDS (R3-measured 0 bank conflicts). 2 barriers/step.
__global__ __launch_bounds__(512, 2) void k_score(
    const float* __restrict__ x, const _Float16* __restrict__ Wp,
    const float* __restrict__ b1, const float* __restrict__ w2,
    float* __restrict__ partials)
{
  __shared__ __align__(16) _Float16 Ahi[128 * 136];   // 34 KB
  __shared__ __align__(16) _Float16 Alo[128 * 136];   // 34 KB
  __shared__ float part_lds[4][128];

  const int tid  = threadIdx.x;
  const int lane = tid & 63;
  const int wave = tid >> 6;
  const int wr = wave >> 2, wn = wave & 3;
  const int l31 = lane & 31, l5 = lane >> 5;

  // XCD-bijective decode (proven FETCH-halving in R5): 4 col-blocks of a
  // row-panel land on one XCD -> panel enters that L2 once.
  const int id  = blockIdx.x;
  const int xcd = id & 7, seq = id >> 3;
  const int px  = seq & 3;                 // col-block 0..3
  const int py  = (seq >> 2) * 8 + xcd;    // row-panel 0..1023
  const int m0 = py * 128;

  // A staging: 4 16B-units/thread/step: unit g covers row ar+g*32, k seg as*..
  const int ar = tid >> 4;                 // 0..31
  const int as = (tid & 15) * 4;           // k offset 0..60 (x4 floats)
  const float* xs = x + (size_t)(m0 + ar) * DDIM + as;

  // B fragment base pointers (per nf): frag (cb*64 + t*4+kc), halves hl in {0,1}
  const _Float16* wpb[2];
#pragma unroll
  for (int nf = 0; nf < 2; nf++)
    wpb[nf] = Wp + (size_t)((px * 8 + wn * 2 + nf) * 64) * 1024 + lane * 8;

  floatx16 acc[2][2] = {};
  float4v xv[4];

#define LOADX(T)                                              \
  _Pragma("unroll")                                           \
  for (int g = 0; g < 4; g++)                                 \
    xv[g] = *(const float4v*)(xs + (size_t)g * 32 * DDIM + (T) * 64);

#define WRITEX()                                              \
  _Pragma("unroll")                                           \
  for (int g = 0; g < 4; g++) {                               \
    half4v hv, lv;                                            \
    _Pragma("unroll")                                         \
    for (int i = 0; i < 4; i++) {                             \
      _Float16 h = (_Float16)xv[g][i];                        \
      hv[i] = h; lv[i] = (_Float16)(xv[g][i] - (float)h);     \
    }                                                         \
    int r = ar + g * 32;                                      \
    *(half4v*)&Ahi[r * 136 + as] = hv;                        \
    *(half4v*)&Alo[r * 136 + as] = lv;                        \
  }

  LOADX(0)
  WRITEX()
  __syncthreads();

#pragma unroll 1
  for (int t = 0; t < 16; ++t) {
    if (t < 15) LOADX(t + 1)                 // T14: consumed ~1500cyc later
    half8 bcur[2][2], bnxt[2][2];
#pragma unroll
    for (int nf = 0; nf < 2; nf++) {
      bnxt[nf][0] = *(const half8*)(wpb[nf] + (size_t)(t * 4 + 0) * 1024);
      bnxt[nf][1] = *(const half8*)(wpb[nf] + (size_t)(t * 4 + 0) * 1024 + 512);
    }
#pragma unroll
    for (int kc = 0; kc < 4; kc++) {
#pragma unroll
      for (int nf = 0; nf < 2; nf++) {
        bcur[nf][0] = bnxt[nf][0];
        bcur[nf][1] = bnxt[nf][1];
      }
      if (kc < 3) {
#pragma unroll
        for (int nf = 0; nf < 2; nf++) {
          bnxt[nf][0] = *(const half8*)(wpb[nf] + (size_t)(t * 4 + kc + 1) * 1024);
          bnxt[nf][1] = *(const half8*)(wpb[nf] + (size_t)(t * 4 + kc + 1) * 1024 + 512);
        }
      }
      half8 ah[2], al[2];
#pragma unroll
      for (int mf = 0; mf < 2; mf++) {
        int r = wr * 64 + mf * 32 + l31;
        ah[mf] = *(const half8*)&Ahi[r * 136 + kc * 16 + l5 * 8];
        al[mf] = *(const half8*)&Alo[r * 136 + kc * 16 + l5 * 8];
      }
#pragma unroll
      for (int mf = 0; mf < 2; mf++)
#pragma unroll
        for (int nf = 0; nf < 2; nf++) {
          acc[mf][nf] = __builtin_amdgcn_mfma_f32_32x32x16_f16(ah[mf], bcur[nf][0], acc[mf][nf], 0, 0, 0);
          acc[mf][nf] = __builtin_amdgcn_mfma_f32_32x32x16_f16(ah[mf], bcur[nf][1], acc[mf][nf], 0, 0, 0);
          acc[mf][nf] = __builtin_amdgcn_mfma_f32_32x32x16_f16(al[mf], bcur[nf][0], acc[mf][nf], 0, 0, 0);
        }
    }
    __syncthreads();                         // all waves done reading A(t)
    if (t < 15) {
      WRITEX()                               // stage A(t+1); vmcnt waits hit old loads
      __syncthreads();                       // A(t+1) visible
    }
  }
#undef LOADX
#undef WRITEX

  // ---- epilogue: tanh + dot(w2) + row reduce ----
  float b1v[2], w2v[2];
#pragma unroll
  for (int nf = 0; nf < 2; nf++) {
    int col = px * 256 + wn * 64 + nf * 32 + l31;
    b1v[nf] = b1[col];
    w2v[nf] = w2[col];
  }
  const float inv512 = 1.0f / 512.0f;
#pragma unroll
  for (int mf = 0; mf < 2; mf++)
#pragma unroll
    for (int reg = 0; reg < 16; reg++) {
      float s = 0.0f;
#pragma unroll
      for (int nf = 0; nf < 2; nf++) {
        float pre = acc[mf][nf][reg] * inv512 + b1v[nf];
        float a = fabsf(pre);
        float e = __expf(-2.0f * a);
        float t = (1.0f - e) / (1.0f + e);            // tanh(|pre|)
        s += copysignf(t, pre) * w2v[nf];
      }
#pragma unroll
      for (int off = 1; off < 32; off <<= 1) s += __shfl_xor(s, off, 64);
      if (l31 == 0)
        part_lds[wn][wr * 64 + mf * 32 + (reg & 3) + 8 * (reg >> 2) + 4 * l5] = s;
    }
  __syncthreads();
  if (tid < 128) {
    float v = part_lds[0][tid] + part_lds[1][tid] + part_lds[2][tid] + part_lds[3][tid];
    partials[(size_t)px * MTOT + m0 + tid] = v;
  }
}

// --------- kernel 2: per-batch-row exact select (stable-argsort semantics) + softmax
__global__ void k_select(const float* __restrict__ partials, const float* __restrict__ b2,
                         float* __restrict__ weights)
{
  __shared__ float s_lds[TLEN];
  __shared__ unsigned long long keys[TLEN];
  __shared__ float red[20];
  const int b = blockIdx.x, tid = threadIdx.x;
  const float b2v = b2[0];

  for (int i = tid; i < TLEN; i += 1024) {
    size_t idx = (size_t)b * TLEN + i;
    float s = partials[idx] + partials[idx + (size_t)MTOT] +
              partials[idx + 2 * (size_t)MTOT] + partials[idx + 3 * (size_t)MTOT] + b2v;
    s_lds[i] = s;
    unsigned u = __float_as_uint(s);
    u = (u & 0x80000000u) ? ~u : (u | 0x80000000u);  // order-preserving float->uint
    keys[i] = ((unsigned long long)u << 32) | (unsigned)i;
  }
  __syncthreads();
  // bitonic sort ascending (key = (score, index) — matches stable argsort)
  for (int k = 2; k <= TLEN; k <<= 1)
    for (int j = k >> 1; j > 0; j >>= 1) {
      for (int i = tid; i < TLEN; i += 1024) {
        int p = i ^ j;
        if (p > i) {
          unsigned long long a = keys[i], c = keys[p];
          bool up = ((i & k) == 0);
          if ((a > c) == up) { keys[i] = c; keys[p] = a; }
        }
      }
      __syncthreads();
    }

  const unsigned long long thr = keys[NMASK];        // first KEPT pair
  unsigned um = (unsigned)(keys[TLEN - 1] >> 32);    // decode row max
  um = (um & 0x80000000u) ? (um ^ 0x80000000u) : ~um;
  const float m = __uint_as_float(um);

  float ev[4]; bool kp[4]; float zp = 0.0f;
#pragma unroll
  for (int q = 0; q < 4; q++) {
    int i = tid + q * 1024;
    float s = s_lds[i];
    unsigned u = __float_as_uint(s);
    u = (u & 0x80000000u) ? ~u : (u | 0x80000000u);
    unsigned long long key = ((unsigned long long)u << 32) | (unsigned)i;
    kp[q] = (key >= thr);
    ev[q] = __expf(s - m);
    if (kp[q]) zp += ev[q];
  }
#pragma unroll
  for (int off = 1; off < 64; off <<= 1) zp += __shfl_xor(zp, off, 64);
  if ((tid & 63) == 0) red[tid >> 6] = zp;
  __syncthreads();
  if (tid == 0) { float z = 0.0f; for (int i = 0; i < 16; i++) z += red[i]; red[16] = z; }
  __syncthreads();
  const float invZ = 1.0f / red[16];
#pragma unroll
  for (int q = 0; q < 4; q++) {
    int i = tid + q * 1024;
    weights[(size_t)b * TLEN + i] = kp[q] ? ev[q] * invZ : 0.0f;
  }
}

// --------- kernel 3: masked_output = x * weights[row] ---------
__global__ void k_scale(const float* __restrict__ x, const float* __restrict__ weights,
                        float* __restrict__ out)
{
  const size_t n4 = (size_t)MTOT * DDIM / 4;
  for (size_t f = (size_t)blockIdx.x * blockDim.x + threadIdx.x; f < n4;
       f += (size_t)gridDim.x * blockDim.x) {
    float w = weights[f >> 8];                       // 256 float4 per row
    float4v v = ((const float4v*)x)[f];
    ((float4v*)out)[f] = v * w;
  }
}

extern "C" void kernel_launch(void* const* d_in, const int* in_sizes, int n_in,
                              void* d_out, int out_size, void* d_ws, size_t ws_size,
                              hipStream_t stream)
{
  const float* x  = (const float*)d_in[0];
  const float* W1 = (const float*)d_in[1];
  const float* b1 = (const float*)d_in[2];
  const float* w2 = (const float*)d_in[3];
  const float* b2 = (const float*)d_in[4];
  float* out = (float*)d_out;
  float* weights = out + (size_t)MTOT * DDIM;        // output 1 region

  // Wp (8 MiB) lives in d_out's masked_output region (dead until k_scale
  // overwrites it at the very end — proven-safe scratch in R4/R5).
  _Float16* Wp = (_Float16*)d_out;
  float* parts = (float*)d_ws;                       // 2 MiB

  k_wpack<<<512, 256, 0, stream>>>(W1, Wp);          // 2048 frags x 4/block
  k_score<<<4096, 512, 0, stream>>>(x, Wp, b1, w2, parts);
  k_select<<<BATCH, 1024, 0, stream>>>(parts, b2, weights);
  k_scale<<<2048, 256, 0, stream>>>(x, weights, out);
}